// Round 16
// baseline (68.736 us; speedup 1.0000x reference)
//
#include <hip/hip_runtime.h>
#include <hip/hip_bf16.h>

// Problem constants (match reference)
#define BATCH   8
#define CDIM    256
#define ODIM    16
#define GRID16  16
#define NCELL   4096            // 16*16*16
#define PADW    17
#define PADV    (PADW*PADW*PADW)
#define MAXK    32              // point chunks per batch (256 blocks total)
#define SENT16  0x007Fu         // mapped bf16 -inf
#define SENTPK  0x007F007Fu
#define TPB     768             // 12 waves = 3/SIMD (R14: 4/SIMD forces 64/64 split)
#define NT      4               // M-tiles (16 pts each) per wave-iteration

// ws layout (u32 words):
//   [0, 1024)      : W1b1 packed float4 per c  (w1x,w1y,w1z,b1)
//   [1024, 3072)   : W2 bf16 MFMA A-fragments, uint4 per (kt*64+lane)
//   [4096, ...)    : Km * BATCH slabs, G-MAJOR: u64[g][4096] per slab
//                    (word index = g*8192 + cell*2 + w; ch = 4g+2w, 4g+2w+1)
#define HDR_WORDS   4096
#define SLAB_WORDS  (8 * 4096)   // 32768 u32 = 128 KiB

typedef __attribute__((ext_vector_type(8))) short bf16x8;
typedef __attribute__((ext_vector_type(4))) float f32x4;
typedef __attribute__((ext_vector_type(4))) unsigned u32x4;
typedef unsigned long long u64;

// ---------------------------------------------------------------------------
__device__ __forceinline__ float unmap16(unsigned m) {
    unsigned r = (m & 0x8000u) ? (m ^ 0x8000u) : (~m & 0xFFFFu);
    return __uint_as_float(r << 16);
}
// packed pair map: per 16-bit field, r ^= (sign ? 0xFFFF : 0x8000)
__device__ __forceinline__ unsigned mpk(unsigned w) {
    return w ^ (0x80008000u | (((w >> 15) & 0x00010001u) * 0x7FFFu));
}
// two fp32 -> packed bf16 pair (lo = first): single HW instruction (T12)
__device__ __forceinline__ unsigned pkbf16(float lo, float hi) {
    unsigned r;
    asm("v_cvt_pk_bf16_f32 %0, %1, %2" : "=v"(r) : "v"(lo), "v"(hi));
    return r;
}
// packed-pair unsigned max per 16-bit field
__device__ __forceinline__ unsigned pmax(unsigned a, unsigned b) {
    unsigned hi = max(a >> 16, b >> 16);
    unsigned lo = max(a & 0xFFFFu, b & 0xFFFFu);
    return (hi << 16) | lo;
}
// 4x bf16-mapped fields in a u64
__device__ __forceinline__ u64 pmax64(u64 a, u64 b) {
    unsigned lo = pmax((unsigned)a, (unsigned)b);
    unsigned hi = pmax((unsigned)(a >> 32), (unsigned)(b >> 32));
    return ((u64)hi << 32) | lo;
}

// ---------------------------------------------------------------------------
__global__ void k_pack2(const float* __restrict__ W1, const float* __restrict__ b1,
                        const float* __restrict__ W2, unsigned* __restrict__ ws) {
    int t = threadIdx.x;                    // 512 threads
    float* w1p = reinterpret_cast<float*>(ws);
    if (t < 256) {
        float4 v;
        v.x = W1[t * 3 + 0];
        v.y = W1[t * 3 + 1];
        v.z = W1[t * 3 + 2];
        v.w = b1[t];
        reinterpret_cast<float4*>(w1p)[t] = v;
    }
    // W2 A fragments, k-map c(kt,j,g) = kt*32 + (j>>2)*16 + 4g + (j&3)
    int kt = t >> 6, l = t & 63;
    int g = (l >> 4), o = l & 15;
    const float* wr = W2 + o * CDIM + kt * 32 + 4 * g;   // base
    uint4 q;
    q.x = pkbf16(wr[0],  wr[1]);
    q.y = pkbf16(wr[2],  wr[3]);
    q.z = pkbf16(wr[16], wr[17]);
    q.w = pkbf16(wr[18], wr[19]);
    reinterpret_cast<uint4*>(ws + 1024)[t] = q;
}

// ---------------------------------------------------------------------------
// fast zero-fill (replaces hipMemsetAsync's fillBufferAligned)
__global__ void k_zero(unsigned* __restrict__ p, int n) {
    int i = blockIdx.x * blockDim.x + threadIdx.x;
    int n4 = n >> 2;
    if (i < n4) {
        u32x4 z = {0u, 0u, 0u, 0u};
        reinterpret_cast<u32x4*>(p)[i] = z;
    }
    if (i == 0) for (int r = n4 << 2; r < n; ++r) p[r] = 0u;
}

// ---------------------------------------------------------------------------
// 64-bit CAS max: one DS atomic covers 4 bf16-mapped fields.
__device__ __forceinline__ void casmax64(u64* addr, u64 wv) {
    u64 cur = *addr;
    while (true) {
        u64 nv = pmax64(cur, wv);
        if (nv == cur) return;
        u64 prev = atomicCAS(addr, cur, nv);
        if (prev == cur) return;
        cur = prev;
    }
}

__device__ __forceinline__ bf16x8 mk_frag(unsigned w0, unsigned w1) {
    u32x4 u = {w0, w1, 0u, 0u};
    return __builtin_bit_cast(bf16x8, u);
}

// ---------------------------------------------------------------------------
// MFMA scatter: block (k, b). 12 waves (3/SIMD); NT=4 16-point M-tiles per
// wave-iteration. Both layers on MFMA, fragments in VGPRs.
//   L1: h[ch16][pt16]  = W1(A) * x(B)            [K=4 of 32 used]
//   L2: D[och16][pt16] = W2(A) * h(B) + b2(C-in) [operand-swapped]
// R16 changes:
//  (1) h/ua hoisted into per-kt arrays: all 8 L1 MFMAs issue before packs,
//      packs before L2s -- forces cross-tile ILP the scheduler serialized
//      away in R13 (VGPR dropped 88->84 = chains were serialized).
//  (2) cm64 is G-MAJOR [g][cell]: same-g lanes spread over 16 bank-pairs
//      (cell%16) instead of 4 (cell%4) -> kills ~4-way atomic conflicts.
__global__ __launch_bounds__(TPB, 1)
void k_scatter_mfma(const float* __restrict__ xin,
                    const unsigned* __restrict__ ws,
                    const float* __restrict__ b2,
                    unsigned* __restrict__ slabs,
                    int nper, int chunk) {
    __shared__ u64 cm64[SLAB_WORDS / 2];     // 128 KiB; [g][4096] u64
    unsigned* cm = reinterpret_cast<unsigned*>(cm64);
    const int kblk = blockIdx.x, b = blockIdx.z;
    const int tid = threadIdx.x;
    const int l = tid & 63, wv = tid >> 6;   // lane, wave (0..11)
    const int g = l >> 4;                    // lane group 0..3
    const bool g0 = (g == 0);
    const int lp = l & 15;                   // point slot within tile

    {   // vectorized sentinel init: 8192 uint4
        u32x4 s = {SENTPK, SENTPK, SENTPK, SENTPK};
        u32x4* cm4 = reinterpret_cast<u32x4*>(cm);
        for (int i = tid; i < SLAB_WORDS / 4; i += TPB) cm4[i] = s;
    }

    // ---- W1 A-fragments (16 channel groups) into registers ----
    bf16x8 w1f[16];
    {
        const float4* w1p = reinterpret_cast<const float4*>(ws);
#pragma unroll
        for (int cg = 0; cg < 16; ++cg) {
            float4 w = w1p[cg * 16 + lp];
            unsigned a0 = g0 ? pkbf16(w.x, w.y) : 0u;
            unsigned a1 = g0 ? pkbf16(w.z, w.w) : 0u;
            w1f[cg] = mk_frag(a0, a1);
        }
    }
    // ---- W2 A-fragments into registers ----
    bf16x8 w2f[8];
#pragma unroll
    for (int kt = 0; kt < 8; ++kt) {
        u32x4 q = reinterpret_cast<const u32x4*>(ws + 1024)[kt * 64 + l];
        w2f[kt] = __builtin_bit_cast(bf16x8, q);
    }
    // L2 C-in: lane holds rows och = 4g..4g+3 -> per-lane bias quad
    float4 b4 = reinterpret_cast<const float4*>(b2)[g];
    const f32x4 bb = {b4.x, b4.y, b4.z, b4.w};
    const f32x4 z4 = {0.f, 0.f, 0.f, 0.f};
    __syncthreads();

    const int p0 = kblk * chunk;
    const int p1 = min(p0 + chunk, nper);
    const float* xb = xin + (size_t)b * nper * 3;
    const int STRIDE = (TPB / 64) * NT * 16; // 768 points per block-iter

    // prefetched x for current iteration
    float cx[NT], cy[NT], cz[NT];
#pragma unroll
    for (int t = 0; t < NT; ++t) {
        int p = min(p0 + wv * (NT * 16) + t * 16 + lp, nper - 1);
        cx[t] = xb[p * 3 + 0]; cy[t] = xb[p * 3 + 1]; cz[t] = xb[p * 3 + 2];
    }

    for (int gb = p0 + wv * (NT * 16); gb < p1; gb += STRIDE) {
        // ---- issue next-iter x loads early (clamped, branchless) ----
        float nx[NT], ny[NT], nz[NT];
#pragma unroll
        for (int t = 0; t < NT; ++t) {
            int p = min(gb + STRIDE + t * 16 + lp, nper - 1);
            nx[t] = xb[p * 3 + 0]; ny[t] = xb[p * 3 + 1]; nz[t] = xb[p * 3 + 2];
        }

        int cell16[NT];
        bf16x8 bx[NT];
#pragma unroll
        for (int t = 0; t < NT; ++t) {
            cell16[t] = ((min(max((int)floorf(cx[t]), 0), 15) << 8) |
                         (min(max((int)floorf(cy[t]), 0), 15) << 4) |
                          min(max((int)floorf(cz[t]), 0), 15));
            bx[t] = mk_frag(g0 ? pkbf16(cx[t], cy[t]) : 0u,
                            g0 ? pkbf16(cz[t], 1.0f) : 0u);
        }

        f32x4 acc[NT];
#pragma unroll
        for (int t = 0; t < NT; ++t) acc[t] = bb;

#pragma unroll
        for (int kt = 0; kt < 8; ++kt) {
            // phase 1: ALL L1 MFMAs (8 independent, latencies overlap)
            f32x4 h0[NT], h1[NT];
#pragma unroll
            for (int t = 0; t < NT; ++t) {
                h0[t] = __builtin_amdgcn_mfma_f32_16x16x32_bf16(w1f[2*kt],   bx[t], z4, 0, 0, 0);
                h1[t] = __builtin_amdgcn_mfma_f32_16x16x32_bf16(w1f[2*kt+1], bx[t], z4, 0, 0, 0);
            }
            // phase 2: ALL relu+packs (VALU, independent of each other)
            u32x4 ua[NT];
#pragma unroll
            for (int t = 0; t < NT; ++t) {
                ua[t][0] = pkbf16(fmaxf(h0[t][0],0.f), fmaxf(h0[t][1],0.f));
                ua[t][1] = pkbf16(fmaxf(h0[t][2],0.f), fmaxf(h0[t][3],0.f));
                ua[t][2] = pkbf16(fmaxf(h1[t][0],0.f), fmaxf(h1[t][1],0.f));
                ua[t][3] = pkbf16(fmaxf(h1[t][2],0.f), fmaxf(h1[t][3],0.f));
            }
            // phase 3: ALL L2 MFMAs (operand-swapped; b2 folded via C-in)
#pragma unroll
            for (int t = 0; t < NT; ++t)
                acc[t] = __builtin_amdgcn_mfma_f32_16x16x32_bf16(
                             w2f[kt], __builtin_bit_cast(bf16x8, ua[t]), acc[t], 0, 0, 0);
        }

        // ---- epilogue per tile: in-lane, ONE u64 casmax per lane ----
#pragma unroll
        for (int t = 0; t < NT; ++t) {
            if (gb + t * 16 + lp < p1) {
                unsigned w01 = mpk(pkbf16(acc[t][0], acc[t][1]));  // ch 4g, 4g+1
                unsigned w23 = mpk(pkbf16(acc[t][2], acc[t][3]));  // ch 4g+2, 4g+3
                u64 wq = ((u64)w23 << 32) | w01;
                casmax64(&cm64[(g << 12) + cell16[t]], wq);        // g-major
            }
        }

#pragma unroll
        for (int t = 0; t < NT; ++t) { cx[t] = nx[t]; cy[t] = ny[t]; cz[t] = nz[t]; }
    }
    __syncthreads();

    // flush slab (flat copy; layout preserved)
    unsigned* dst = slabs + (size_t)(kblk * BATCH + b) * SLAB_WORDS;
    uint4* d4 = reinterpret_cast<uint4*>(dst);
    const uint4* s4 = reinterpret_cast<const uint4*>(cm);
    for (int i = tid; i < SLAB_WORDS / 4; i += TPB) d4[i] = s4[i];
}

// ---------------------------------------------------------------------------
// reduce K slabs -> out interior. thread = (b, cell). G-major slab layout:
// word = g*8192 + cell*2 + w; holds channels 4g+2w, 4g+2w+1 (= m[2g+w]).
__global__ __launch_bounds__(256)
void k_reduce3(const unsigned* __restrict__ slabs, float* __restrict__ out, int K) {
    int t = blockIdx.x * 256 + threadIdx.x;
    if (t >= BATCH * NCELL) return;
    int cell = t & (NCELL - 1), b = t >> 12;

    unsigned m[8];
#pragma unroll
    for (int i = 0; i < 8; ++i) m[i] = SENTPK;

    for (int k = 0; k < K; ++k) {
        const unsigned* s = slabs + (size_t)(k * BATCH + b) * SLAB_WORDS + cell * 2;
#pragma unroll
        for (int g = 0; g < 4; ++g) {
            uint2 a = *reinterpret_cast<const uint2*>(s + g * 8192);
            m[2*g]     = pmax(m[2*g],     a.x);
            m[2*g + 1] = pmax(m[2*g + 1], a.y);
        }
    }

    int ix = cell >> 8, iy = (cell >> 4) & 15, iz = cell & 15;
    size_t obase = ((size_t)b * ODIM) * PADV + ((ix * PADW + iy) * PADW + iz);
#pragma unroll
    for (int op = 0; op < 8; ++op) {
        unsigned lo = m[op] & 0xFFFFu, hi = m[op] >> 16;
        out[obase + (size_t)(2 * op)     * PADV] = (lo == SENT16) ? 0.0f : unmap16(lo);
        out[obase + (size_t)(2 * op + 1) * PADV] = (hi == SENT16) ? 0.0f : unmap16(hi);
    }
}

// ===========================================================================
// Fallback (round-1): direct global atomics. Used only if ws too small.
__global__ void k_init(unsigned* __restrict__ out, int total) {
    int i = blockIdx.x * blockDim.x + threadIdx.x;
    if (i >= total) return;
    int r = i % PADV;
    int z = r % PADW, y = (r / PADW) % PADW, x = r / (PADW * PADW);
    out[i] = (x < GRID16 && y < GRID16 && z < GRID16) ? 0xFF800000u : 0u;
}
__device__ __forceinline__ void atomicMaxFloat(float* addr, float v) {
    if (v >= 0.0f) atomicMax(reinterpret_cast<int*>(addr), __float_as_int(v));
    else           atomicMin(reinterpret_cast<unsigned*>(addr), __float_as_uint(v));
}
__global__ __launch_bounds__(256)
void k_scatter_glb(const float* __restrict__ xin,
                   const float* __restrict__ W1, const float* __restrict__ b1,
                   const float* __restrict__ W2, const float* __restrict__ b2,
                   float* __restrict__ out, int npts, int nper) {
    int p = blockIdx.x * 256 + threadIdx.x;
    if (p >= npts) return;
    float x0 = xin[p*3+0], x1 = xin[p*3+1], x2 = xin[p*3+2];
    float acc[ODIM];
#pragma unroll
    for (int o = 0; o < ODIM; ++o) acc[o] = b2[o];
#pragma unroll 2
    for (int c = 0; c < CDIM; ++c) {
        float h = fmaf(W1[c*3+0], x0, fmaf(W1[c*3+1], x1, fmaf(W1[c*3+2], x2, b1[c])));
        h = fmaxf(h, 0.0f);
#pragma unroll
        for (int o = 0; o < ODIM; ++o) acc[o] = fmaf(W2[o*CDIM+c], h, acc[o]);
    }
    int ix = min(max((int)floorf(x0), 0), GRID16-1);
    int iy = min(max((int)floorf(x1), 0), GRID16-1);
    int iz = min(max((int)floorf(x2), 0), GRID16-1);
    int b = p / nper;
    size_t base = ((((size_t)b*ODIM)*PADW + ix)*PADW + iy)*PADW + iz;
#pragma unroll
    for (int o = 0; o < ODIM; ++o)
        atomicMaxFloat(out + base + (size_t)o*PADV, acc[o]);
}
__global__ void k_final(unsigned* __restrict__ out, int total) {
    int i = blockIdx.x * blockDim.x + threadIdx.x;
    if (i >= total) return;
    if (out[i] == 0xFF800000u) out[i] = 0u;
}

// ===========================================================================
extern "C" void kernel_launch(void* const* d_in, const int* in_sizes, int n_in,
                              void* d_out, int out_size, void* d_ws, size_t ws_size,
                              hipStream_t stream) {
    const float* x  = (const float*)d_in[0];
    const float* W1 = (const float*)d_in[1];
    const float* b1 = (const float*)d_in[2];
    const float* W2 = (const float*)d_in[3];
    const float* b2 = (const float*)d_in[4];
    float* out = (float*)d_out;

    int npts = in_sizes[0] / 3;          // B*N
    int nper = npts / BATCH;             // N

    size_t ws_words = ws_size / 4;
    int Km = 0;
    if (ws_words > HDR_WORDS) {
        size_t avail = (ws_words - HDR_WORDS) / ((size_t)BATCH * SLAB_WORDS);
        Km = (int)min((size_t)MAXK, avail);
    }

    if (Km >= 1) {
        unsigned* ws = (unsigned*)d_ws;
        k_pack2<<<1, 512, 0, stream>>>(W1, b1, W2, ws);
        int zb = (out_size / 4 + 255) / 256;
        k_zero<<<zb, 256, 0, stream>>>((unsigned*)out, out_size);

        unsigned* slabs = ws + HDR_WORDS;
        int chunk = (nper + Km - 1) / Km;
        dim3 grid(Km, 1, BATCH);
        k_scatter_mfma<<<grid, TPB, 0, stream>>>(x, ws, b2, slabs, nper, chunk);

        int rt = BATCH * NCELL;
        k_reduce3<<<(rt + 255) / 256, 256, 0, stream>>>(slabs, out, Km);
    } else {
        int total = out_size;
        k_init<<<(total + 255) / 256, 256, 0, stream>>>((unsigned*)out, total);
        int blocks = (npts + 255) / 256;
        k_scatter_glb<<<blocks, 256, 0, stream>>>(x, W1, b1, W2, b2, out, npts, nper);
        k_final<<<(total + 255) / 256, 256, 0, stream>>>((unsigned*)out, total);
    }
}

// Round 17
// 66.324 us; speedup vs baseline: 1.0364x; 1.0364x over previous
//
#include <hip/hip_runtime.h>
#include <hip/hip_bf16.h>

// Problem constants (match reference)
#define BATCH   8
#define CDIM    256
#define ODIM    16
#define GRID16  16
#define NCELL   4096            // 16*16*16
#define PADW    17
#define PADV    (PADW*PADW*PADW)
#define MAXK    32              // point chunks per batch (256 blocks total)
#define SENT16  0x007Fu         // mapped bf16 -inf
#define SENTPK  0x007F007Fu
#define TPB     1024            // 16 waves = 4/SIMD; arch cap 64 -> W-frags in LDS
#define NT      2               // M-tiles (16 pts each) per wave-iteration

// ws layout (u32 words):
//   [0, 2048)      : W2 bf16 MFMA A-fragments, u32x4 per (kt*64+lane)
//   [2048, 6144)   : W1 bf16 MFMA A-fragments, u32x4 per (cg*64+lane)
//                    (zeros for lane groups g>0; K=4 of 32 used)
//   [8192, ...)    : Km * BATCH slabs, G-MAJOR: u64[g][4096] per slab
#define HDR_WORDS   8192
#define SLAB_WORDS  (8 * 4096)   // 32768 u32 = 128 KiB

typedef __attribute__((ext_vector_type(8))) short bf16x8;
typedef __attribute__((ext_vector_type(4))) float f32x4;
typedef __attribute__((ext_vector_type(4))) unsigned u32x4;
typedef unsigned long long u64;

// ---------------------------------------------------------------------------
__device__ __forceinline__ float unmap16(unsigned m) {
    unsigned r = (m & 0x8000u) ? (m ^ 0x8000u) : (~m & 0xFFFFu);
    return __uint_as_float(r << 16);
}
__device__ __forceinline__ unsigned mpk(unsigned w) {
    return w ^ (0x80008000u | (((w >> 15) & 0x00010001u) * 0x7FFFu));
}
__device__ __forceinline__ unsigned pkbf16(float lo, float hi) {
    unsigned r;
    asm("v_cvt_pk_bf16_f32 %0, %1, %2" : "=v"(r) : "v"(lo), "v"(hi));
    return r;
}
__device__ __forceinline__ unsigned pmax(unsigned a, unsigned b) {
    unsigned hi = max(a >> 16, b >> 16);
    unsigned lo = max(a & 0xFFFFu, b & 0xFFFFu);
    return (hi << 16) | lo;
}
__device__ __forceinline__ u64 pmax64(u64 a, u64 b) {
    unsigned lo = pmax((unsigned)a, (unsigned)b);
    unsigned hi = pmax((unsigned)(a >> 32), (unsigned)(b >> 32));
    return ((u64)hi << 32) | lo;
}

// ---------------------------------------------------------------------------
// Pack W2 and W1 MFMA A-fragments (k-map c(kt,j,g)=kt*32+(j>>2)*16+4g+(j&3)).
__global__ void k_pack2(const float* __restrict__ W1, const float* __restrict__ b1,
                        const float* __restrict__ W2, unsigned* __restrict__ ws) {
    int t = threadIdx.x;                    // 1024 threads
    if (t < 512) {
        int kt = t >> 6, l = t & 63;
        int g = (l >> 4), o = l & 15;
        const float* wr = W2 + o * CDIM + kt * 32 + 4 * g;
        uint4 q;
        q.x = pkbf16(wr[0],  wr[1]);
        q.y = pkbf16(wr[2],  wr[3]);
        q.z = pkbf16(wr[16], wr[17]);
        q.w = pkbf16(wr[18], wr[19]);
        reinterpret_cast<uint4*>(ws)[t] = q;
    }
    // W1 A-fragment item t: cg = t>>6, lane l = t&63
    {
        int cg = t >> 6, l = t & 63;
        int lp = l & 15, g = l >> 4;
        int c = cg * 16 + lp;
        uint4 q = {0u, 0u, 0u, 0u};
        if (g == 0) {
            q.x = pkbf16(W1[c * 3 + 0], W1[c * 3 + 1]);
            q.y = pkbf16(W1[c * 3 + 2], b1[c]);
        }
        reinterpret_cast<uint4*>(ws + 2048)[t] = q;
    }
}

// ---------------------------------------------------------------------------
__global__ void k_zero(unsigned* __restrict__ p, int n) {
    int i = blockIdx.x * blockDim.x + threadIdx.x;
    int n4 = n >> 2;
    if (i < n4) {
        u32x4 z = {0u, 0u, 0u, 0u};
        reinterpret_cast<u32x4*>(p)[i] = z;
    }
    if (i == 0) for (int r = n4 << 2; r < n; ++r) p[r] = 0u;
}

// ---------------------------------------------------------------------------
__device__ __forceinline__ void casmax64(u64* addr, u64 wv) {
    u64 cur = *addr;
    while (true) {
        u64 nv = pmax64(cur, wv);
        if (nv == cur) return;
        u64 prev = atomicCAS(addr, cur, nv);
        if (prev == cur) return;
        cur = prev;
    }
}

__device__ __forceinline__ bf16x8 mk_frag(unsigned w0, unsigned w1) {
    u32x4 u = {w0, w1, 0u, 0u};
    return __builtin_bit_cast(bf16x8, u);
}

// ---------------------------------------------------------------------------
// MFMA scatter: block (k, b). 16 waves (4/SIMD); NT=2 16-pt M-tiles/iter.
//   L1: h[ch16][pt16]  = W1(A, LDS frag) * x(B)
//   L2: D[och16][pt16] = W2(A, LDS frag) * h(B) + b2(C-in)
// R17: W1/W2 fragments moved to LDS (was 64 arch VGPRs) + NT=2 -> arch live
// ~55 < 64, fitting the 64/64 arch/acc split the allocator forces at
// 4 waves/SIMD (R14). TLP 3->4 waves/SIMD is the only lever that has moved
// the wall (R13). LDS: 128K grid + 16K w1 + 8K w2 = 152K <= 160K.
__global__ __launch_bounds__(TPB, 1)
void k_scatter_mfma(const float* __restrict__ xin,
                    const unsigned* __restrict__ ws,
                    const float* __restrict__ b2,
                    unsigned* __restrict__ slabs,
                    int nper, int chunk) {
    __shared__ u64 cm64[SLAB_WORDS / 2];     // 128 KiB; [g][4096] u64
    __shared__ u32x4 w1fs[1024];             // 16 KiB
    __shared__ u32x4 w2fs[512];              // 8 KiB
    unsigned* cm = reinterpret_cast<unsigned*>(cm64);
    const int kblk = blockIdx.x, b = blockIdx.z;
    const int tid = threadIdx.x;
    const int l = tid & 63, wv = tid >> 6;   // lane, wave (0..15)
    const int g = l >> 4;                    // lane group 0..3
    const bool g0 = (g == 0);
    const int lp = l & 15;                   // point slot within tile

    w1fs[tid] = reinterpret_cast<const u32x4*>(ws + 2048)[tid];
    if (tid < 512)
        w2fs[tid] = reinterpret_cast<const u32x4*>(ws)[tid];
    {   // sentinel init: 8192 uint4 / 1024 threads
        u32x4 s = {SENTPK, SENTPK, SENTPK, SENTPK};
        u32x4* cm4 = reinterpret_cast<u32x4*>(cm);
        for (int i = tid; i < SLAB_WORDS / 4; i += TPB) cm4[i] = s;
    }
    float4 b4 = reinterpret_cast<const float4*>(b2)[g];
    const f32x4 bb = {b4.x, b4.y, b4.z, b4.w};
    const f32x4 z4 = {0.f, 0.f, 0.f, 0.f};
    __syncthreads();

    const int p0 = kblk * chunk;
    const int p1 = min(p0 + chunk, nper);
    const float* xb = xin + (size_t)b * nper * 3;
    const int STRIDE = (TPB / 64) * NT * 16; // 512 points per block-iter

    float cx[NT], cy[NT], cz[NT];
#pragma unroll
    for (int t = 0; t < NT; ++t) {
        int p = min(p0 + wv * (NT * 16) + t * 16 + lp, nper - 1);
        cx[t] = xb[p * 3 + 0]; cy[t] = xb[p * 3 + 1]; cz[t] = xb[p * 3 + 2];
    }

    for (int gb = p0 + wv * (NT * 16); gb < p1; gb += STRIDE) {
        // issue next-iter x loads early (clamped, branchless)
        float nx[NT], ny[NT], nz[NT];
#pragma unroll
        for (int t = 0; t < NT; ++t) {
            int p = min(gb + STRIDE + t * 16 + lp, nper - 1);
            nx[t] = xb[p * 3 + 0]; ny[t] = xb[p * 3 + 1]; nz[t] = xb[p * 3 + 2];
        }

        int cell16[NT];
        bf16x8 bx[NT];
#pragma unroll
        for (int t = 0; t < NT; ++t) {
            cell16[t] = ((min(max((int)floorf(cx[t]), 0), 15) << 8) |
                         (min(max((int)floorf(cy[t]), 0), 15) << 4) |
                          min(max((int)floorf(cz[t]), 0), 15));
            bx[t] = mk_frag(g0 ? pkbf16(cx[t], cy[t]) : 0u,
                            g0 ? pkbf16(cz[t], 1.0f) : 0u);
        }

        f32x4 acc[NT];
#pragma unroll
        for (int t = 0; t < NT; ++t) acc[t] = bb;

#pragma unroll
        for (int kt = 0; kt < 8; ++kt) {
            // fragment reads from LDS (shared across tiles)
            u32x4 a0 = w1fs[(2 * kt) * 64 + l];      // ds_read_b128
            u32x4 a1 = w1fs[(2 * kt + 1) * 64 + l];
            u32x4 wq = w2fs[kt * 64 + l];
            bf16x8 w1a = __builtin_bit_cast(bf16x8, a0);
            bf16x8 w1b = __builtin_bit_cast(bf16x8, a1);
            bf16x8 w2a = __builtin_bit_cast(bf16x8, wq);
#pragma unroll
            for (int t = 0; t < NT; ++t) {
                f32x4 h0 = __builtin_amdgcn_mfma_f32_16x16x32_bf16(w1a, bx[t], z4, 0, 0, 0);
                f32x4 h1 = __builtin_amdgcn_mfma_f32_16x16x32_bf16(w1b, bx[t], z4, 0, 0, 0);
                u32x4 ua;
                ua[0] = pkbf16(fmaxf(h0[0],0.f), fmaxf(h0[1],0.f));
                ua[1] = pkbf16(fmaxf(h0[2],0.f), fmaxf(h0[3],0.f));
                ua[2] = pkbf16(fmaxf(h1[0],0.f), fmaxf(h1[1],0.f));
                ua[3] = pkbf16(fmaxf(h1[2],0.f), fmaxf(h1[3],0.f));
                acc[t] = __builtin_amdgcn_mfma_f32_16x16x32_bf16(
                             w2a, __builtin_bit_cast(bf16x8, ua), acc[t], 0, 0, 0);
            }
        }

        // epilogue per tile: in-lane, ONE u64 casmax per lane (g-major grid)
#pragma unroll
        for (int t = 0; t < NT; ++t) {
            if (gb + t * 16 + lp < p1) {
                unsigned w01 = mpk(pkbf16(acc[t][0], acc[t][1]));
                unsigned w23 = mpk(pkbf16(acc[t][2], acc[t][3]));
                u64 wq = ((u64)w23 << 32) | w01;
                casmax64(&cm64[(g << 12) + cell16[t]], wq);
            }
        }

#pragma unroll
        for (int t = 0; t < NT; ++t) { cx[t] = nx[t]; cy[t] = ny[t]; cz[t] = nz[t]; }
    }
    __syncthreads();

    // flush slab (flat copy; layout preserved)
    unsigned* dst = slabs + (size_t)(kblk * BATCH + b) * SLAB_WORDS;
    uint4* d4 = reinterpret_cast<uint4*>(dst);
    const uint4* s4 = reinterpret_cast<const uint4*>(cm);
    for (int i = tid; i < SLAB_WORDS / 4; i += TPB) d4[i] = s4[i];
}

// ---------------------------------------------------------------------------
// reduce K slabs -> out interior. G-major slab layout:
// word = g*8192 + cell*2 + w; holds channels 4g+2w, 4g+2w+1.
__global__ __launch_bounds__(256)
void k_reduce3(const unsigned* __restrict__ slabs, float* __restrict__ out, int K) {
    int t = blockIdx.x * 256 + threadIdx.x;
    if (t >= BATCH * NCELL) return;
    int cell = t & (NCELL - 1), b = t >> 12;

    unsigned m[8];
#pragma unroll
    for (int i = 0; i < 8; ++i) m[i] = SENTPK;

    for (int k = 0; k < K; ++k) {
        const unsigned* s = slabs + (size_t)(k * BATCH + b) * SLAB_WORDS + cell * 2;
#pragma unroll
        for (int g = 0; g < 4; ++g) {
            uint2 a = *reinterpret_cast<const uint2*>(s + g * 8192);
            m[2*g]     = pmax(m[2*g],     a.x);
            m[2*g + 1] = pmax(m[2*g + 1], a.y);
        }
    }

    int ix = cell >> 8, iy = (cell >> 4) & 15, iz = cell & 15;
    size_t obase = ((size_t)b * ODIM) * PADV + ((ix * PADW + iy) * PADW + iz);
#pragma unroll
    for (int op = 0; op < 8; ++op) {
        unsigned lo = m[op] & 0xFFFFu, hi = m[op] >> 16;
        out[obase + (size_t)(2 * op)     * PADV] = (lo == SENT16) ? 0.0f : unmap16(lo);
        out[obase + (size_t)(2 * op + 1) * PADV] = (hi == SENT16) ? 0.0f : unmap16(hi);
    }
}

// ===========================================================================
// Fallback (round-1): direct global atomics. Used only if ws too small.
__global__ void k_init(unsigned* __restrict__ out, int total) {
    int i = blockIdx.x * blockDim.x + threadIdx.x;
    if (i >= total) return;
    int r = i % PADV;
    int z = r % PADW, y = (r / PADW) % PADW, x = r / (PADW * PADW);
    out[i] = (x < GRID16 && y < GRID16 && z < GRID16) ? 0xFF800000u : 0u;
}
__device__ __forceinline__ void atomicMaxFloat(float* addr, float v) {
    if (v >= 0.0f) atomicMax(reinterpret_cast<int*>(addr), __float_as_int(v));
    else           atomicMin(reinterpret_cast<unsigned*>(addr), __float_as_uint(v));
}
__global__ __launch_bounds__(256)
void k_scatter_glb(const float* __restrict__ xin,
                   const float* __restrict__ W1, const float* __restrict__ b1,
                   const float* __restrict__ W2, const float* __restrict__ b2,
                   float* __restrict__ out, int npts, int nper) {
    int p = blockIdx.x * 256 + threadIdx.x;
    if (p >= npts) return;
    float x0 = xin[p*3+0], x1 = xin[p*3+1], x2 = xin[p*3+2];
    float acc[ODIM];
#pragma unroll
    for (int o = 0; o < ODIM; ++o) acc[o] = b2[o];
#pragma unroll 2
    for (int c = 0; c < CDIM; ++c) {
        float h = fmaf(W1[c*3+0], x0, fmaf(W1[c*3+1], x1, fmaf(W1[c*3+2], x2, b1[c])));
        h = fmaxf(h, 0.0f);
#pragma unroll
        for (int o = 0; o < ODIM; ++o) acc[o] = fmaf(W2[o*CDIM+c], h, acc[o]);
    }
    int ix = min(max((int)floorf(x0), 0), GRID16-1);
    int iy = min(max((int)floorf(x1), 0), GRID16-1);
    int iz = min(max((int)floorf(x2), 0), GRID16-1);
    int b = p / nper;
    size_t base = ((((size_t)b*ODIM)*PADW + ix)*PADW + iy)*PADW + iz;
#pragma unroll
    for (int o = 0; o < ODIM; ++o)
        atomicMaxFloat(out + base + (size_t)o*PADV, acc[o]);
}
__global__ void k_final(unsigned* __restrict__ out, int total) {
    int i = blockIdx.x * blockDim.x + threadIdx.x;
    if (i >= total) return;
    if (out[i] == 0xFF800000u) out[i] = 0u;
}

// ===========================================================================
extern "C" void kernel_launch(void* const* d_in, const int* in_sizes, int n_in,
                              void* d_out, int out_size, void* d_ws, size_t ws_size,
                              hipStream_t stream) {
    const float* x  = (const float*)d_in[0];
    const float* W1 = (const float*)d_in[1];
    const float* b1 = (const float*)d_in[2];
    const float* W2 = (const float*)d_in[3];
    const float* b2 = (const float*)d_in[4];
    float* out = (float*)d_out;

    int npts = in_sizes[0] / 3;          // B*N
    int nper = npts / BATCH;             // N

    size_t ws_words = ws_size / 4;
    int Km = 0;
    if (ws_words > HDR_WORDS) {
        size_t avail = (ws_words - HDR_WORDS) / ((size_t)BATCH * SLAB_WORDS);
        Km = (int)min((size_t)MAXK, avail);
    }

    if (Km >= 1) {
        unsigned* ws = (unsigned*)d_ws;
        k_pack2<<<1, 1024, 0, stream>>>(W1, b1, W2, ws);
        int zb = (out_size / 4 + 255) / 256;
        k_zero<<<zb, 256, 0, stream>>>((unsigned*)out, out_size);

        unsigned* slabs = ws + HDR_WORDS;
        int chunk = (nper + Km - 1) / Km;
        dim3 grid(Km, 1, BATCH);
        k_scatter_mfma<<<grid, TPB, 0, stream>>>(x, ws, b2, slabs, nper, chunk);

        int rt = BATCH * NCELL;
        k_reduce3<<<(rt + 255) / 256, 256, 0, stream>>>(slabs, out, Km);
    } else {
        int total = out_size;
        k_init<<<(total + 255) / 256, 256, 0, stream>>>((unsigned*)out, total);
        int blocks = (npts + 255) / 256;
        k_scatter_glb<<<blocks, 256, 0, stream>>>(x, W1, b1, W2, b2, out, npts, nper);
        k_final<<<(total + 255) / 256, 256, 0, stream>>>((unsigned*)out, total);
    }
}

// Round 18
// 65.883 us; speedup vs baseline: 1.0433x; 1.0067x over previous
//
#include <hip/hip_runtime.h>
#include <hip/hip_bf16.h>

// Problem constants (match reference)
#define BATCH   8
#define CDIM    256
#define ODIM    16
#define GRID16  16
#define NCELL   4096            // 16*16*16
#define PADW    17
#define PADV    (PADW*PADW*PADW)
#define MAXK    32              // point chunks per batch (256 blocks total)
#define SENT16  0x007Fu         // mapped bf16 -inf
#define SENTPK  0x007F007Fu
#define TPB     1024            // 16 waves = 4/SIMD; arch cap 64 -> W-frags in LDS
#define NT      2               // M-tiles (16 pts each) per wave-iteration
#define NPAD    817             // padding cells per (b, och) plane (17^3 - 16^3... per-plane)

// ws layout (u32 words):
//   [0, 2048)      : W2 bf16 MFMA A-fragments, u32x4 per (kt*64+lane)
//   [2048, 4096)   : W1 bf16 MFMA A-fragments, uint2 per (cg*64+lane)
//                    (only 2 words live: K=4 of 32 used; g>0 lanes zero)
//   [8192, ...)    : Km * BATCH slabs, G-MAJOR: u64[g][4096] per slab
#define HDR_WORDS   8192
#define SLAB_WORDS  (8 * 4096)   // 32768 u32 = 128 KiB

typedef __attribute__((ext_vector_type(8))) short bf16x8;
typedef __attribute__((ext_vector_type(4))) float f32x4;
typedef __attribute__((ext_vector_type(4))) unsigned u32x4;
typedef unsigned long long u64;

// ---------------------------------------------------------------------------
__device__ __forceinline__ float unmap16(unsigned m) {
    unsigned r = (m & 0x8000u) ? (m ^ 0x8000u) : (~m & 0xFFFFu);
    return __uint_as_float(r << 16);
}
__device__ __forceinline__ unsigned mpk(unsigned w) {
    return w ^ (0x80008000u | (((w >> 15) & 0x00010001u) * 0x7FFFu));
}
__device__ __forceinline__ unsigned pkbf16(float lo, float hi) {
    unsigned r;
    asm("v_cvt_pk_bf16_f32 %0, %1, %2" : "=v"(r) : "v"(lo), "v"(hi));
    return r;
}
__device__ __forceinline__ unsigned pmax(unsigned a, unsigned b) {
    unsigned hi = max(a >> 16, b >> 16);
    unsigned lo = max(a & 0xFFFFu, b & 0xFFFFu);
    return (hi << 16) | lo;
}
__device__ __forceinline__ u64 pmax64(u64 a, u64 b) {
    unsigned lo = pmax((unsigned)a, (unsigned)b);
    unsigned hi = pmax((unsigned)(a >> 32), (unsigned)(b >> 32));
    return ((u64)hi << 32) | lo;
}

// ---------------------------------------------------------------------------
// Pack W2 (u32x4) and W1 (uint2) MFMA A-fragments.
// k-map c(kt,j,g) = kt*32 + (j>>2)*16 + 4g + (j&3).
__global__ void k_pack2(const float* __restrict__ W1, const float* __restrict__ b1,
                        const float* __restrict__ W2, unsigned* __restrict__ ws) {
    int t = threadIdx.x;                    // 1024 threads
    if (t < 512) {
        int kt = t >> 6, l = t & 63;
        int g = (l >> 4), o = l & 15;
        const float* wr = W2 + o * CDIM + kt * 32 + 4 * g;
        uint4 q;
        q.x = pkbf16(wr[0],  wr[1]);
        q.y = pkbf16(wr[2],  wr[3]);
        q.z = pkbf16(wr[16], wr[17]);
        q.w = pkbf16(wr[18], wr[19]);
        reinterpret_cast<uint4*>(ws)[t] = q;
    }
    // W1 A-fragment item t: cg = t>>6, lane l = t&63; only 2 live words
    {
        int cg = t >> 6, l = t & 63;
        int lp = l & 15, g = l >> 4;
        int c = cg * 16 + lp;
        uint2 q = {0u, 0u};
        if (g == 0) {
            q.x = pkbf16(W1[c * 3 + 0], W1[c * 3 + 1]);
            q.y = pkbf16(W1[c * 3 + 2], b1[c]);
        }
        reinterpret_cast<uint2*>(ws + 2048)[t] = q;
    }
}

// ---------------------------------------------------------------------------
__device__ __forceinline__ void casmax64(u64* addr, u64 wv) {
    u64 cur = *addr;
    while (true) {
        u64 nv = pmax64(cur, wv);
        if (nv == cur) return;
        u64 prev = atomicCAS(addr, cur, nv);
        if (prev == cur) return;
        cur = prev;
    }
}

__device__ __forceinline__ bf16x8 mk_frag(unsigned w0, unsigned w1) {
    u32x4 u = {w0, w1, 0u, 0u};
    return __builtin_bit_cast(bf16x8, u);
}

// ---------------------------------------------------------------------------
// MFMA scatter: block (k, b). 16 waves (4/SIMD); NT=2 16-pt M-tiles/iter.
//   L1: h[ch16][pt16]  = W1(A, LDS b64 frag) * x(B)
//   L2: D[och16][pt16] = W2(A, LDS b128 frag) * h(B) + b2(C-in)
// R18 probe: W1 frags as uint2 -> 2x ds_read_b64 + 1x ds_read_b128 per kt
// (was 3x b128, half-zero payload). ~28% inner-loop DS-pipe cut -- the last
// unprobed shared resource consistent with R13->R17's wave-count flatness.
__global__ __launch_bounds__(TPB, 1)
void k_scatter_mfma(const float* __restrict__ xin,
                    const unsigned* __restrict__ ws,
                    const float* __restrict__ b2,
                    unsigned* __restrict__ slabs,
                    int nper, int chunk) {
    __shared__ u64 cm64[SLAB_WORDS / 2];     // 128 KiB; [g][4096] u64
    __shared__ uint2 w1fs[1024];             // 8 KiB
    __shared__ u32x4 w2fs[512];              // 8 KiB
    unsigned* cm = reinterpret_cast<unsigned*>(cm64);
    const int kblk = blockIdx.x, b = blockIdx.z;
    const int tid = threadIdx.x;
    const int l = tid & 63, wv = tid >> 6;   // lane, wave (0..15)
    const int g = l >> 4;                    // lane group 0..3
    const bool g0 = (g == 0);
    const int lp = l & 15;                   // point slot within tile

    w1fs[tid] = reinterpret_cast<const uint2*>(ws + 2048)[tid];
    if (tid < 512)
        w2fs[tid] = reinterpret_cast<const u32x4*>(ws)[tid];
    {   // sentinel init: 8192 uint4 / 1024 threads
        u32x4 s = {SENTPK, SENTPK, SENTPK, SENTPK};
        u32x4* cm4 = reinterpret_cast<u32x4*>(cm);
        for (int i = tid; i < SLAB_WORDS / 4; i += TPB) cm4[i] = s;
    }
    float4 b4 = reinterpret_cast<const float4*>(b2)[g];
    const f32x4 bb = {b4.x, b4.y, b4.z, b4.w};
    const f32x4 z4 = {0.f, 0.f, 0.f, 0.f};
    __syncthreads();

    const int p0 = kblk * chunk;
    const int p1 = min(p0 + chunk, nper);
    const float* xb = xin + (size_t)b * nper * 3;
    const int STRIDE = (TPB / 64) * NT * 16; // 512 points per block-iter

    float cx[NT], cy[NT], cz[NT];
#pragma unroll
    for (int t = 0; t < NT; ++t) {
        int p = min(p0 + wv * (NT * 16) + t * 16 + lp, nper - 1);
        cx[t] = xb[p * 3 + 0]; cy[t] = xb[p * 3 + 1]; cz[t] = xb[p * 3 + 2];
    }

    for (int gb = p0 + wv * (NT * 16); gb < p1; gb += STRIDE) {
        // issue next-iter x loads early (clamped, branchless)
        float nx[NT], ny[NT], nz[NT];
#pragma unroll
        for (int t = 0; t < NT; ++t) {
            int p = min(gb + STRIDE + t * 16 + lp, nper - 1);
            nx[t] = xb[p * 3 + 0]; ny[t] = xb[p * 3 + 1]; nz[t] = xb[p * 3 + 2];
        }

        int cell16[NT];
        bf16x8 bx[NT];
#pragma unroll
        for (int t = 0; t < NT; ++t) {
            cell16[t] = ((min(max((int)floorf(cx[t]), 0), 15) << 8) |
                         (min(max((int)floorf(cy[t]), 0), 15) << 4) |
                          min(max((int)floorf(cz[t]), 0), 15));
            bx[t] = mk_frag(g0 ? pkbf16(cx[t], cy[t]) : 0u,
                            g0 ? pkbf16(cz[t], 1.0f) : 0u);
        }

        f32x4 acc[NT];
#pragma unroll
        for (int t = 0; t < NT; ++t) acc[t] = bb;

#pragma unroll
        for (int kt = 0; kt < 8; ++kt) {
            // fragment reads from LDS: 2x b64 (W1) + 1x b128 (W2)
            uint2 a0 = w1fs[(2 * kt) * 64 + l];
            uint2 a1 = w1fs[(2 * kt + 1) * 64 + l];
            u32x4 wq = w2fs[kt * 64 + l];
            bf16x8 w1a = mk_frag(a0.x, a0.y);
            bf16x8 w1b = mk_frag(a1.x, a1.y);
            bf16x8 w2a = __builtin_bit_cast(bf16x8, wq);
#pragma unroll
            for (int t = 0; t < NT; ++t) {
                f32x4 h0 = __builtin_amdgcn_mfma_f32_16x16x32_bf16(w1a, bx[t], z4, 0, 0, 0);
                f32x4 h1 = __builtin_amdgcn_mfma_f32_16x16x32_bf16(w1b, bx[t], z4, 0, 0, 0);
                u32x4 ua;
                ua[0] = pkbf16(fmaxf(h0[0],0.f), fmaxf(h0[1],0.f));
                ua[1] = pkbf16(fmaxf(h0[2],0.f), fmaxf(h0[3],0.f));
                ua[2] = pkbf16(fmaxf(h1[0],0.f), fmaxf(h1[1],0.f));
                ua[3] = pkbf16(fmaxf(h1[2],0.f), fmaxf(h1[3],0.f));
                acc[t] = __builtin_amdgcn_mfma_f32_16x16x32_bf16(
                             w2a, __builtin_bit_cast(bf16x8, ua), acc[t], 0, 0, 0);
            }
        }

        // epilogue per tile: in-lane, ONE u64 casmax per lane (g-major grid)
#pragma unroll
        for (int t = 0; t < NT; ++t) {
            if (gb + t * 16 + lp < p1) {
                unsigned w01 = mpk(pkbf16(acc[t][0], acc[t][1]));
                unsigned w23 = mpk(pkbf16(acc[t][2], acc[t][3]));
                u64 wq = ((u64)w23 << 32) | w01;
                casmax64(&cm64[(g << 12) + cell16[t]], wq);
            }
        }

#pragma unroll
        for (int t = 0; t < NT; ++t) { cx[t] = nx[t]; cy[t] = ny[t]; cz[t] = nz[t]; }
    }
    __syncthreads();

    // flush slab (flat copy; layout preserved)
    unsigned* dst = slabs + (size_t)(kblk * BATCH + b) * SLAB_WORDS;
    uint4* d4 = reinterpret_cast<uint4*>(dst);
    const uint4* s4 = reinterpret_cast<const uint4*>(cm);
    for (int i = tid; i < SLAB_WORDS / 4; i += TPB) d4[i] = s4[i];
}

// ---------------------------------------------------------------------------
// reduce K slabs -> out interior; extra threads write the zero padding
// (fused: replaces the separate k_zero launch + 2.5MB redundant fill).
// G-major slab: word = g*8192 + cell*2 + w; channels 4g+2w, 4g+2w+1.
__global__ __launch_bounds__(256)
void k_reduce4(const unsigned* __restrict__ slabs, float* __restrict__ out, int K) {
    int t = blockIdx.x * 256 + threadIdx.x;
    if (t < BATCH * NCELL) {
        int cell = t & (NCELL - 1), b = t >> 12;

        unsigned m[8];
#pragma unroll
        for (int i = 0; i < 8; ++i) m[i] = SENTPK;

        for (int k = 0; k < K; ++k) {
            const unsigned* s = slabs + (size_t)(k * BATCH + b) * SLAB_WORDS + cell * 2;
#pragma unroll
            for (int g = 0; g < 4; ++g) {
                uint2 a = *reinterpret_cast<const uint2*>(s + g * 8192);
                m[2*g]     = pmax(m[2*g],     a.x);
                m[2*g + 1] = pmax(m[2*g + 1], a.y);
            }
        }

        int ix = cell >> 8, iy = (cell >> 4) & 15, iz = cell & 15;
        size_t obase = ((size_t)b * ODIM) * PADV + ((ix * PADW + iy) * PADW + iz);
#pragma unroll
        for (int op = 0; op < 8; ++op) {
            unsigned lo = m[op] & 0xFFFFu, hi = m[op] >> 16;
            out[obase + (size_t)(2 * op)     * PADV] = (lo == SENT16) ? 0.0f : unmap16(lo);
            out[obase + (size_t)(2 * op + 1) * PADV] = (hi == SENT16) ? 0.0f : unmap16(hi);
        }
    } else {
        // padding writer: one thread per padding word
        int pt = t - BATCH * NCELL;
        if (pt >= BATCH * ODIM * NPAD) return;
        int bo = pt / NPAD;                 // (b*ODIM + och), 0..127
        int r  = pt - bo * NPAD;
        int x, y, z;
        if (r < 289)      { x = 16; y = r / 17; z = r - (r / 17) * 17; }
        else if (r < 561) { int r2 = r - 289; x = r2 / 17; y = 16; z = r2 - (r2 / 17) * 17; }
        else              { int r3 = r - 561; x = r3 >> 4; y = r3 & 15; z = 16; }
        out[(size_t)bo * PADV + (x * PADW + y) * PADW + z] = 0.0f;
    }
}

// ===========================================================================
// Fallback (round-1): direct global atomics. Used only if ws too small.
__global__ void k_init(unsigned* __restrict__ out, int total) {
    int i = blockIdx.x * blockDim.x + threadIdx.x;
    if (i >= total) return;
    int r = i % PADV;
    int z = r % PADW, y = (r / PADW) % PADW, x = r / (PADW * PADW);
    out[i] = (x < GRID16 && y < GRID16 && z < GRID16) ? 0xFF800000u : 0u;
}
__device__ __forceinline__ void atomicMaxFloat(float* addr, float v) {
    if (v >= 0.0f) atomicMax(reinterpret_cast<int*>(addr), __float_as_int(v));
    else           atomicMin(reinterpret_cast<unsigned*>(addr), __float_as_uint(v));
}
__global__ __launch_bounds__(256)
void k_scatter_glb(const float* __restrict__ xin,
                   const float* __restrict__ W1, const float* __restrict__ b1,
                   const float* __restrict__ W2, const float* __restrict__ b2,
                   float* __restrict__ out, int npts, int nper) {
    int p = blockIdx.x * 256 + threadIdx.x;
    if (p >= npts) return;
    float x0 = xin[p*3+0], x1 = xin[p*3+1], x2 = xin[p*3+2];
    float acc[ODIM];
#pragma unroll
    for (int o = 0; o < ODIM; ++o) acc[o] = b2[o];
#pragma unroll 2
    for (int c = 0; c < CDIM; ++c) {
        float h = fmaf(W1[c*3+0], x0, fmaf(W1[c*3+1], x1, fmaf(W1[c*3+2], x2, b1[c])));
        h = fmaxf(h, 0.0f);
#pragma unroll
        for (int o = 0; o < ODIM; ++o) acc[o] = fmaf(W2[o*CDIM+c], h, acc[o]);
    }
    int ix = min(max((int)floorf(x0), 0), GRID16-1);
    int iy = min(max((int)floorf(x1), 0), GRID16-1);
    int iz = min(max((int)floorf(x2), 0), GRID16-1);
    int b = p / nper;
    size_t base = ((((size_t)b*ODIM)*PADW + ix)*PADW + iy)*PADW + iz;
#pragma unroll
    for (int o = 0; o < ODIM; ++o)
        atomicMaxFloat(out + base + (size_t)o*PADV, acc[o]);
}
__global__ void k_final(unsigned* __restrict__ out, int total) {
    int i = blockIdx.x * blockDim.x + threadIdx.x;
    if (i >= total) return;
    if (out[i] == 0xFF800000u) out[i] = 0u;
}

// ===========================================================================
extern "C" void kernel_launch(void* const* d_in, const int* in_sizes, int n_in,
                              void* d_out, int out_size, void* d_ws, size_t ws_size,
                              hipStream_t stream) {
    const float* x  = (const float*)d_in[0];
    const float* W1 = (const float*)d_in[1];
    const float* b1 = (const float*)d_in[2];
    const float* W2 = (const float*)d_in[3];
    const float* b2 = (const float*)d_in[4];
    float* out = (float*)d_out;

    int npts = in_sizes[0] / 3;          // B*N
    int nper = npts / BATCH;             // N

    size_t ws_words = ws_size / 4;
    int Km = 0;
    if (ws_words > HDR_WORDS) {
        size_t avail = (ws_words - HDR_WORDS) / ((size_t)BATCH * SLAB_WORDS);
        Km = (int)min((size_t)MAXK, avail);
    }

    if (Km >= 1) {
        unsigned* ws = (unsigned*)d_ws;
        k_pack2<<<1, 1024, 0, stream>>>(W1, b1, W2, ws);

        unsigned* slabs = ws + HDR_WORDS;
        int chunk = (nper + Km - 1) / Km;
        dim3 grid(Km, 1, BATCH);
        k_scatter_mfma<<<grid, TPB, 0, stream>>>(x, ws, b2, slabs, nper, chunk);

        int rt = BATCH * NCELL + BATCH * ODIM * NPAD;  // interior + padding
        k_reduce4<<<(rt + 255) / 256, 256, 0, stream>>>(slabs, out, Km);
    } else {
        int total = out_size;
        k_init<<<(total + 255) / 256, 256, 0, stream>>>((unsigned*)out, total);
        int blocks = (npts + 255) / 256;
        k_scatter_glb<<<blocks, 256, 0, stream>>>(x, W1, b1, W2, b2, out, npts, nper);
        k_final<<<(total + 255) / 256, 256, 0, stream>>>((unsigned*)out, total);
    }
}